// Round 10
// baseline (2453.144 us; speedup 1.0000x reference)
//
#include <hip/hip_runtime.h>

static constexpr int BTRIALS = 32;
static constexpr int TSTEPS  = 512;
static constexpr int IDIM    = 64;
static constexpr int NDIM    = 4096;
static constexpr int RDIM    = 8;
static constexpr int ODIM    = 64;

// pipeline geometry
static constexpr int TC   = 64;                 // scan steps per chunk
static constexpr int NCH  = TSTEPS / TC;        // 8 chunks
static constexpr int SCAN_BLOCKS  = 32;
static constexpr int TOTAL_BLOCKS = 256;
static constexpr int WORKER_WAVES = (TOTAL_BLOCKS - SCAN_BLOCKS) * 8;  // 1792
static constexpr int PRE_TASKS_PER_CHUNK = 512; // (TC*32 rows /16) * 4 col-quarters
static constexpr int PRE_TASKS = NCH * PRE_TASKS_PER_CHUNK;  // 4096
static constexpr int Y_TASKS_PER_CHUNK = 256;   // 32 b * 4 t-tiles * 2 o-halves
static constexpr int Y_TASKS = NCH * Y_TASKS_PER_CHUNK;      // 2048

// flags layout (in ws, 64B-strided): flags[c*16] = pre_done[c] (target 512)
//                                    flags[128 + b*16] = scan_prog[b] (chunks done)

typedef short v8s __attribute__((ext_vector_type(8)));
typedef float v4f __attribute__((ext_vector_type(4)));

__device__ __forceinline__ float fast_sigmoid(float x) {
    float e = __builtin_amdgcn_exp2f(x * -1.44269504088896340736f);
    return __builtin_amdgcn_rcpf(1.0f + e);
}

__device__ __forceinline__ float2 pk_fma(float2 a, float2 b, float2 c) {
    float2 d;
    asm("v_pk_fma_f32 %0, %1, %2, %3" : "=v"(d) : "v"(a), "v"(b), "v"(c));
    return d;
}

template <int CTRL, int RMASK>
__device__ __forceinline__ float dpp_add(float v) {
    int moved = __builtin_amdgcn_update_dpp(0, __float_as_int(v), CTRL, RMASK, 0xf, true);
    return v + __int_as_float(moved);
}

__device__ __forceinline__ float wave_reduce_to_lane63(float v) {
    v = dpp_add<0x111, 0xf>(v);
    v = dpp_add<0x112, 0xf>(v);
    v = dpp_add<0x114, 0xf>(v);
    v = dpp_add<0x118, 0xf>(v);
    v = dpp_add<0x142, 0xa>(v);
    v = dpp_add<0x143, 0xc>(v);
    return v;
}

__device__ __forceinline__ short f2bf(float f) {
    unsigned u = __float_as_uint(f);
    u += 0x7FFFu + ((u >> 16) & 1u);   // RNE
    return (short)(u >> 16);
}

// ---------------------------------------------------------------------------
// Split fp32 stream into bf16 hi/lo pair (optionally pre-scaled).
// ---------------------------------------------------------------------------
__global__ __launch_bounds__(256) void split_conv(const float* __restrict__ src,
                                                  unsigned short* __restrict__ hi,
                                                  unsigned short* __restrict__ lo,
                                                  float scale) {
    const int base = (blockIdx.x * 256 + threadIdx.x) * 8;
    float4 a = *(const float4*)(src + base);
    float4 b = *(const float4*)(src + base + 4);
    float v[8] = {a.x, a.y, a.z, a.w, b.x, b.y, b.z, b.w};
    v8s h, l;
    #pragma unroll
    for (int j = 0; j < 8; ++j) {
        float f  = v[j] * scale;
        short hb = f2bf(f);
        h[j] = hb;
        float fh = __uint_as_float(((unsigned)(unsigned short)hb) << 16);
        l[j] = f2bf(f - fh);
    }
    *(v8s*)(hi + base) = h;
    *(v8s*)(lo + base) = l;
}

// ---------------------------------------------------------------------------
// W fp32 -> bf16, once; block 0 also zeroes the pipeline flags (runs before
// mega in stream order).
// ---------------------------------------------------------------------------
__global__ __launch_bounds__(256) void wconv(const float* __restrict__ W,
                                             unsigned short* __restrict__ Wb,
                                             unsigned* __restrict__ flags) {
    if (blockIdx.x == 0) {
        for (int i = threadIdx.x; i < 1024; i += 256) flags[i] = 0;
    }
    const int base = (blockIdx.x * 256 + threadIdx.x) * 8;
    float4 a = *(const float4*)(W + base);
    float4 b = *(const float4*)(W + base + 4);
    v8s o;
    o[0] = f2bf(a.x); o[1] = f2bf(a.y); o[2] = f2bf(a.z); o[3] = f2bf(a.w);
    o[4] = f2bf(b.x); o[5] = f2bf(b.y); o[6] = f2bf(b.z); o[7] = f2bf(b.w);
    *(v8s*)(Wb + base) = o;
}

// ---------------------------------------------------------------------------
// Fused pipeline kernel. Blocks 0..31: serial scan (r8 arithmetic, chunked).
// Blocks 32..255: workers — pre_gemm tasks (publish pre_done[c]), then
// y_gemm tasks (gated on scan_prog[b]).
// ---------------------------------------------------------------------------
__global__ __launch_bounds__(512) void mega(const unsigned short* __restrict__ Ah,
                                            const unsigned short* __restrict__ Al,
                                            const unsigned short* __restrict__ Bh,
                                            const unsigned short* __restrict__ Bl,
                                            const float* __restrict__ mmat,
                                            const float* __restrict__ nmat,
                                            float* __restrict__ u,
                                            float* __restrict__ xseq,
                                            unsigned short* __restrict__ sbuf,
                                            const unsigned short* __restrict__ Wb,
                                            float* __restrict__ yout,
                                            unsigned* __restrict__ flags) {
    __shared__ __align__(16) float wlds[2][64];
    const int tid  = threadIdx.x;
    const int lane = tid & 63;

    if (blockIdx.x < SCAN_BLOCKS) {
        // ==================== scan role ====================
        const int b  = blockIdx.x;
        const int j0 = tid * 8;
        const int wv = tid >> 6;

        float2 nmp[4][8], mmp[4][8], x2[4], sp[4];
        const float mscale = 0.1f / 4096.0f;
        #pragma unroll
        for (int jp = 0; jp < 4; ++jp) {
            const float4* na = (const float4*)(nmat + (size_t)(j0 + 2 * jp) * RDIM);
            float4 a0 = na[0], a1 = na[1], b0 = na[2], b1 = na[3];
            nmp[jp][0] = {a0.x, b0.x}; nmp[jp][1] = {a0.y, b0.y};
            nmp[jp][2] = {a0.z, b0.z}; nmp[jp][3] = {a0.w, b0.w};
            nmp[jp][4] = {a1.x, b1.x}; nmp[jp][5] = {a1.y, b1.y};
            nmp[jp][6] = {a1.z, b1.z}; nmp[jp][7] = {a1.w, b1.w};
            const float4* ma = (const float4*)(mmat + (size_t)(j0 + 2 * jp) * RDIM);
            float4 d0 = ma[0], d1 = ma[1], e0 = ma[2], e1 = ma[3];
            mmp[jp][0] = {d0.x * mscale, e0.x * mscale}; mmp[jp][1] = {d0.y * mscale, e0.y * mscale};
            mmp[jp][2] = {d0.z * mscale, e0.z * mscale}; mmp[jp][3] = {d0.w * mscale, e0.w * mscale};
            mmp[jp][4] = {d1.x * mscale, e1.x * mscale}; mmp[jp][5] = {d1.y * mscale, e1.y * mscale};
            mmp[jp][6] = {d1.z * mscale, e1.z * mscale}; mmp[jp][7] = {d1.w * mscale, e1.w * mscale};
        }

        #pragma unroll
        for (int jp = 0; jp < 4; ++jp) x2[jp] = {0.f, 0.f};
        {
            float* z = xseq + (size_t)b * (TSTEPS + 1) * NDIM + j0;
            *(float4*)(z + 0) = make_float4(0.f, 0.f, 0.f, 0.f);
            *(float4*)(z + 4) = make_float4(0.f, 0.f, 0.f, 0.f);
        }
        #pragma unroll
        for (int jp = 0; jp < 4; ++jp)
            sp[jp] = {fast_sigmoid(x2[jp].x), fast_sigmoid(x2[jp].y)};

        const float2 c09 = {0.9f, 0.9f};

        for (int c = 0; c < NCH; ++c) {
            // gate: u chunk c fully produced
            if (tid == 0) {
                unsigned spins = 0;
                while (__hip_atomic_load(&flags[c * 16], __ATOMIC_ACQUIRE,
                                         __HIP_MEMORY_SCOPE_AGENT) < (unsigned)PRE_TASKS_PER_CHUNK) {
                    if (++spins > 50000000u) break;
                }
            }
            __syncthreads();

            const int tbase = c * TC;
            float2 uvp[4];
            {
                const float* up = u + ((size_t)tbase * BTRIALS + b) * NDIM + j0;
                float4 v0 = *(const float4*)(up + 0);
                float4 v1 = *(const float4*)(up + 4);
                uvp[0] = {v0.x, v0.y}; uvp[1] = {v0.z, v0.w};
                uvp[2] = {v1.x, v1.y}; uvp[3] = {v1.z, v1.w};
            }

            for (int tl = 0; tl < TC; ++tl) {
                const int t   = tbase + tl;
                const int buf = tl & 1;
                const int tn  = tbase + ((tl + 1 < TC) ? tl + 1 : TC - 1);
                const float* upn = u + ((size_t)tn * BTRIALS + b) * NDIM + j0;
                float4 pf0 = *(const float4*)(upn + 0);
                float4 pf1 = *(const float4*)(upn + 4);

                float2 p2[8];
                #pragma unroll
                for (int r = 0; r < 8; ++r) p2[r] = {0.f, 0.f};
                #pragma unroll
                for (int jp = 0; jp < 4; ++jp) {
                    #pragma unroll
                    for (int r = 0; r < 8; ++r) p2[r] = pk_fma(sp[jp], nmp[jp][r], p2[r]);
                }
                float part[8];
                #pragma unroll
                for (int r = 0; r < 8; ++r) part[r] = p2[r].x + p2[r].y;
                #pragma unroll
                for (int r = 0; r < 8; ++r) part[r] = wave_reduce_to_lane63(part[r]);

                if (lane == 63) {
                    #pragma unroll
                    for (int r = 0; r < 8; ++r) wlds[buf][r * 8 + wv] = part[r];
                }

                float2 xd2[4];
                #pragma unroll
                for (int jp = 0; jp < 4; ++jp) xd2[jp] = pk_fma(c09, x2[jp], uvp[jp]);

                __syncthreads();

                float v = wlds[buf][lane];
                v = dpp_add<0x111, 0xf>(v);
                v = dpp_add<0x112, 0xf>(v);
                v = dpp_add<0x114, 0xf>(v);

                float ps[8];
                #pragma unroll
                for (int r = 0; r < 8; ++r)
                    ps[r] = __int_as_float(__builtin_amdgcn_readlane(__float_as_int(v), r * 8 + 7));

                #pragma unroll
                for (int r = 0; r < 8; ++r) {
                    float2 psr = {ps[r], ps[r]};
                    #pragma unroll
                    for (int jp = 0; jp < 4; ++jp) xd2[jp] = pk_fma(psr, mmp[jp][r], xd2[jp]);
                }
                #pragma unroll
                for (int jp = 0; jp < 4; ++jp) x2[jp] = xd2[jp];

                float* xrow = xseq + ((size_t)b * (TSTEPS + 1) + (t + 1)) * NDIM + j0;
                *(float4*)(xrow + 0) = make_float4(x2[0].x, x2[0].y, x2[1].x, x2[1].y);
                *(float4*)(xrow + 4) = make_float4(x2[2].x, x2[2].y, x2[3].x, x2[3].y);

                #pragma unroll
                for (int jp = 0; jp < 4; ++jp)
                    sp[jp] = {fast_sigmoid(x2[jp].x), fast_sigmoid(x2[jp].y)};
                int c0, c1, c2, c3;
                asm("v_cvt_pk_bf16_f32 %0, %1, %2" : "=v"(c0) : "v"(sp[0].x), "v"(sp[0].y));
                asm("v_cvt_pk_bf16_f32 %0, %1, %2" : "=v"(c1) : "v"(sp[1].x), "v"(sp[1].y));
                asm("v_cvt_pk_bf16_f32 %0, %1, %2" : "=v"(c2) : "v"(sp[2].x), "v"(sp[2].y));
                asm("v_cvt_pk_bf16_f32 %0, %1, %2" : "=v"(c3) : "v"(sp[3].x), "v"(sp[3].y));
                // device-scope (write-through) stores so chunk publish needs no L2 flush
                unsigned long long s0 = (unsigned)c0 | ((unsigned long long)(unsigned)c1 << 32);
                unsigned long long s1 = (unsigned)c2 | ((unsigned long long)(unsigned)c3 << 32);
                unsigned long long* sp8 =
                    (unsigned long long*)(sbuf + ((size_t)b * TSTEPS + t) * NDIM + j0);
                __hip_atomic_store(sp8 + 0, s0, __ATOMIC_RELAXED, __HIP_MEMORY_SCOPE_AGENT);
                __hip_atomic_store(sp8 + 1, s1, __ATOMIC_RELAXED, __HIP_MEMORY_SCOPE_AGENT);

                uvp[0] = {pf0.x, pf0.y}; uvp[1] = {pf0.z, pf0.w};
                uvp[2] = {pf1.x, pf1.y}; uvp[3] = {pf1.z, pf1.w};
            }

            // publish: all waves drained by the barrier, then release the flag
            __syncthreads();
            if (tid == 0)
                __hip_atomic_store(&flags[128 + b * 16], (unsigned)(c + 1),
                                   __ATOMIC_RELEASE, __HIP_MEMORY_SCOPE_AGENT);
        }
    } else {
        // ==================== worker role ====================
        const int gw = (blockIdx.x - SCAN_BLOCKS) * 8 + (tid >> 6);
        const int lm = lane & 15;
        const int kq = lane >> 4;

        // ---- pre_gemm tasks (chunk-major ids; no gating needed) ----
        for (int T = gw; T < PRE_TASKS; T += WORKER_WAVES) {
            const int c = T >> 9;            // /512
            const int w = T & 511;
            const int btile = c * 128 + (w >> 2);   // global 16-row tile
            const int n0 = (w & 3) * 1024;
            const int mloc = btile * 16 + lm;
            const int bb = mloc & 31;
            const int t  = mloc >> 5;
            const size_t arow = (size_t)bb * TSTEPS + t;

            const unsigned short* pah = Ah + arow * IDIM + kq * 8;
            const unsigned short* pal = Al + arow * IDIM + kq * 8;
            v8s ah0 = *(const v8s*)(pah);
            v8s ah1 = *(const v8s*)(pah + 32);
            v8s al0 = *(const v8s*)(pal);
            v8s al1 = *(const v8s*)(pal + 32);

            const int urow = btile * 16 + kq * 4;

            #pragma unroll 2
            for (int nt = 0; nt < 64; ++nt) {
                const int n = n0 + nt * 16 + lm;
                const unsigned short* pbh = Bh + (size_t)n * IDIM + kq * 8;
                const unsigned short* pbl = Bl + (size_t)n * IDIM + kq * 8;
                v8s bh0 = *(const v8s*)(pbh);
                v8s bh1 = *(const v8s*)(pbh + 32);
                v8s bl0 = *(const v8s*)(pbl);
                v8s bl1 = *(const v8s*)(pbl + 32);
                v4f acc = (v4f){0.f, 0.f, 0.f, 0.f};
                acc = __builtin_amdgcn_mfma_f32_16x16x32_bf16(ah0, bl0, acc, 0, 0, 0);
                acc = __builtin_amdgcn_mfma_f32_16x16x32_bf16(al0, bh0, acc, 0, 0, 0);
                acc = __builtin_amdgcn_mfma_f32_16x16x32_bf16(ah1, bl1, acc, 0, 0, 0);
                acc = __builtin_amdgcn_mfma_f32_16x16x32_bf16(al1, bh1, acc, 0, 0, 0);
                acc = __builtin_amdgcn_mfma_f32_16x16x32_bf16(ah0, bh0, acc, 0, 0, 0);
                acc = __builtin_amdgcn_mfma_f32_16x16x32_bf16(ah1, bh1, acc, 0, 0, 0);
                float* up = u + (size_t)urow * NDIM + n0 + nt * 16 + lm;
                #pragma unroll
                for (int r = 0; r < 4; ++r)
                    __hip_atomic_store(up + (size_t)r * NDIM, acc[r],
                                       __ATOMIC_RELAXED, __HIP_MEMORY_SCOPE_AGENT);
            }
            // release covers the whole wave's outstanding stores (vmcnt is per-wave)
            if (lane == 0)
                __hip_atomic_fetch_add(&flags[c * 16], 1u,
                                       __ATOMIC_RELEASE, __HIP_MEMORY_SCOPE_AGENT);
        }

        // ---- y_gemm tasks, gated on per-trial scan progress ----
        for (int Y = gw; Y < Y_TASKS; Y += WORKER_WAVES) {
            const int c   = Y >> 8;          // /256
            const int rem = Y & 255;
            const int bb  = rem >> 3;
            const int ttl = (rem >> 1) & 3;
            const int ob  = (rem & 1) << 1;  // o-tile base 0 or 2
            const int ttile = c * 4 + ttl;   // global 16-step tile

            if (lane == 0) {
                unsigned spins = 0;
                while (__hip_atomic_load(&flags[128 + bb * 16], __ATOMIC_ACQUIRE,
                                         __HIP_MEMORY_SCOPE_AGENT) < (unsigned)(c + 1)) {
                    if (++spins > 50000000u) break;
                }
            }
            asm volatile("" ::: "memory");

            const unsigned short* pa =
                sbuf + ((size_t)bb * TSTEPS + ttile * 16 + lm) * NDIM + kq * 8;
            const unsigned short* pw0 = Wb + (size_t)(ob * 16 + lm) * NDIM + kq * 8;
            const unsigned short* pw1 = pw0 + (size_t)16 * NDIM;

            v4f acc0 = (v4f){0.f, 0.f, 0.f, 0.f};
            v4f acc1 = (v4f){0.f, 0.f, 0.f, 0.f};

            #pragma unroll 4
            for (int kc = 0; kc < NDIM; kc += 32) {
                v8s af  = *(const v8s*)(pa + kc);
                v8s bf0 = *(const v8s*)(pw0 + kc);
                v8s bf1 = *(const v8s*)(pw1 + kc);
                acc0 = __builtin_amdgcn_mfma_f32_16x16x32_bf16(af, bf0, acc0, 0, 0, 0);
                acc1 = __builtin_amdgcn_mfma_f32_16x16x32_bf16(af, bf1, acc1, 0, 0, 0);
            }

            #pragma unroll
            for (int r = 0; r < 4; ++r) {
                const int row = bb * TSTEPS + ttile * 16 + kq * 4 + r;
                yout[(size_t)row * ODIM + (ob + 0) * 16 + lm] = acc0[r];
                yout[(size_t)row * ODIM + (ob + 1) * 16 + lm] = acc1[r];
            }
        }
    }
}

extern "C" void kernel_launch(void* const* d_in, const int* in_sizes, int n_in,
                              void* d_out, int out_size, void* d_ws, size_t ws_size,
                              hipStream_t stream) {
    const float* inp = (const float*)d_in[0];   // [32][512][64]
    const float* Bm  = (const float*)d_in[1];   // [4096][64]
    const float* Wm  = (const float*)d_in[2];   // [64][4096]
    const float* mm  = (const float*)d_in[3];   // [4096][8]
    const float* nm  = (const float*)d_in[4];   // [4096][8]

    float* out  = (float*)d_out;
    float* xseq = out;                                          // [32][513][4096]
    float* yout = out + (size_t)BTRIALS * (TSTEPS + 1) * NDIM;  // [32][512][64]

    // ws: flags (in old xstate region, 512KB reserved) | Wb | Ah | Al | Bh | Bl
    //     | ubuf fp32 [512][32][4096] | sbuf bf16 [32][512][4096]
    unsigned* flags    = (unsigned*)d_ws;                                    // 4KB used
    float* xregion     = (float*)d_ws;                                       // 512KB reserved
    unsigned short* Wb = (unsigned short*)(xregion + (size_t)BTRIALS * NDIM);
    unsigned short* Ah = Wb + (size_t)ODIM * NDIM;                           // 2 MB
    unsigned short* Al = Ah + (size_t)BTRIALS * TSTEPS * IDIM;               // 2 MB
    unsigned short* Bh = Al + (size_t)BTRIALS * TSTEPS * IDIM;               // 512 KB
    unsigned short* Bl = Bh + (size_t)NDIM * IDIM;                           // 512 KB
    float* ubuf        = (float*)(Bl + (size_t)NDIM * IDIM);
    unsigned short* sbuf = (unsigned short*)(ubuf + (size_t)TSTEPS * BTRIALS * NDIM);

    // wconv also zeroes flags; runs before mega in stream order
    wconv<<<(ODIM * NDIM) / (256 * 8), 256, 0, stream>>>(Wm, Wb, flags);
    split_conv<<<(BTRIALS * TSTEPS * IDIM) / (256 * 8), 256, 0, stream>>>(inp, Ah, Al, 0.1f);
    split_conv<<<(NDIM * IDIM) / (256 * 8), 256, 0, stream>>>(Bm, Bh, Bl, 1.0f);

    mega<<<TOTAL_BLOCKS, 512, 0, stream>>>(Ah, Al, Bh, Bl, mm, nm,
                                           ubuf, xseq, sbuf, Wb, yout, flags);
}